// Round 6
// baseline (537.906 us; speedup 1.0000x reference)
//
#include <hip/hip_runtime.h>
#include <hip/hip_fp16.h>

#define NUM_USERS 100000
#define NUM_ITEMS 150000
#define NN (NUM_USERS + NUM_ITEMS)   // 250000
#define EMBED_DIM 64
#define NNZ_TOT 4000000
#define D4 16                        // 8-byte chunks per row (64 halfs)
#define BROWS 512                    // rows per bucket
#define NBUCK 489                    // ceil(NN / BROWS)
#define EPB 8192                     // edges per block in build passes
#define NBLK 489                     // ceil(NNZ / EPB)
#define HISTN (NBUCK * NBLK)         // 239121

struct __align__(8) h4 { __half2 a, b; };   // 4 halfs = 8 B (one row chunk per lane)

// ---------------- fp16 copy of concat(user,item) ----------------
__global__ __launch_bounds__(256) void lg_cvt(const float* __restrict__ ue,
                                              const float* __restrict__ ie,
                                              h4* __restrict__ x0h) {
    int i = blockIdx.x * 256 + threadIdx.x;          // chunk index, NN*16 total
    if (i >= NN * D4) return;
    float4 v;
    if (i < NUM_USERS * D4) v = ((const float4*)ue)[i];
    else                    v = ((const float4*)ie)[i - NUM_USERS * D4];
    h4 o;
    o.a = __floats2half2_rn(v.x, v.y);
    o.b = __floats2half2_rn(v.z, v.w);
    x0h[i] = o;
}

// ---------------- Pass A: per-block per-bucket histogram (LDS only) ----------------
__global__ __launch_bounds__(256) void lg_histA(const int* __restrict__ rows,
                                                int* __restrict__ histG) {
    __shared__ int cnt[NBUCK];
    int t = threadIdx.x;
    for (int j = t; j < NBUCK; j += 256) cnt[j] = 0;
    __syncthreads();
    int e0 = blockIdx.x * EPB;
    #pragma unroll
    for (int k = 0; k < 32; ++k) {
        int e = e0 + k * 256 + t;
        if (e < NNZ_TOT) atomicAdd(&cnt[rows[e] >> 9], 1);
    }
    __syncthreads();
    for (int j = t; j < NBUCK; j += 256) histG[j * NBLK + blockIdx.x] = cnt[j];
}

// ---------------- scan over HISTN ints ----------------
__global__ __launch_bounds__(256) void lg_scan1(const int* __restrict__ in,
                                                int* __restrict__ out,
                                                int* __restrict__ bsums, int n) {
    __shared__ int sm[256];
    int t = threadIdx.x;
    int i = blockIdx.x * 256 + t;
    int v = (i < n) ? in[i] : 0;
    sm[t] = v;
    __syncthreads();
    for (int off = 1; off < 256; off <<= 1) {
        int add = (t >= off) ? sm[t - off] : 0;
        __syncthreads();
        sm[t] += add;
        __syncthreads();
    }
    if (i < n) out[i] = sm[t] - v;                  // exclusive within chunk
    if (t == 255) bsums[blockIdx.x] = sm[t];
}

__global__ __launch_bounds__(1024) void lg_scan2(int* __restrict__ bsums, int nb) {
    __shared__ int sm[1024];
    int t = threadIdx.x;
    int v = (t < nb) ? bsums[t] : 0;
    sm[t] = v;
    __syncthreads();
    for (int off = 1; off < 1024; off <<= 1) {
        int add = (t >= off) ? sm[t - off] : 0;
        __syncthreads();
        sm[t] += add;
        __syncthreads();
    }
    if (t < nb) bsums[t] = sm[t] - v;               // exclusive offsets
}

__global__ __launch_bounds__(256) void lg_scan3(int* __restrict__ data,
                                                const int* __restrict__ bsums, int n) {
    int i = blockIdx.x * 256 + threadIdx.x;
    if (i < n) data[i] += bsums[blockIdx.x];
}

// ---------------- Pass B: deterministic bucket-grouped scatter, 8 B records ----------------
__global__ __launch_bounds__(256) void lg_scatB(const int* __restrict__ rows,
                                                const int* __restrict__ cols,
                                                const float* __restrict__ vals,
                                                const int* __restrict__ baseG,
                                                int2* __restrict__ rec) {
    __shared__ int cnt[NBUCK];
    __shared__ int base[NBUCK];
    int t = threadIdx.x, b = blockIdx.x;
    for (int j = t; j < NBUCK; j += 256) { cnt[j] = 0; base[j] = baseG[j * NBLK + b]; }
    __syncthreads();
    int e0 = b * EPB;
    #pragma unroll
    for (int k = 0; k < 32; ++k) {
        int e = e0 + k * 256 + t;
        if (e < NNZ_TOT) {
            int r = rows[e];
            int j = r >> 9;
            int loc = atomicAdd(&cnt[j], 1);
            // packed: col in bits [9..26], row_local in bits [0..8]
            rec[base[j] + loc] = make_int2((cols[e] << 9) | (r & 511),
                                           __float_as_int(vals[e]));
        }
    }
}

// ---------------- Pass C: per-bucket CSR finalize (LDS hist + scan + scatter) ----------------
__global__ __launch_bounds__(1024) void lg_csrC(const int2* __restrict__ rec,
                                                const int* __restrict__ baseG,
                                                int* __restrict__ row_start,
                                                int2* __restrict__ edge8) {
    __shared__ int sm[BROWS];
    int j = blockIdx.x, t = threadIdx.x;
    int lo = baseG[j * NBLK];
    int hi = (j + 1 < NBUCK) ? baseG[(j + 1) * NBLK] : NNZ_TOT;
    if (t < BROWS) sm[t] = 0;
    __syncthreads();
    for (int e = lo + t; e < hi; e += 1024) atomicAdd(&sm[rec[e].x & 511], 1);
    __syncthreads();
    int v = (t < BROWS) ? sm[t] : 0;
    for (int off = 1; off < BROWS; off <<= 1) {
        int add = (t >= off && t < BROWS) ? sm[t - off] : 0;
        __syncthreads();
        if (t < BROWS) sm[t] += add;
        __syncthreads();
    }
    int excl = (t < BROWS) ? sm[t] - v : 0;
    int grow = j * BROWS + t;
    if (t < BROWS && grow <= NN) row_start[grow] = lo + excl;  // covers sentinel
    __syncthreads();
    if (t < BROWS) sm[t] = excl;                    // becomes fill counter
    __syncthreads();
    for (int e = lo + t; e < hi; e += 1024) {
        int2 r = rec[e];                            // L2-hot (65 KB window, 2nd sweep)
        int pos = lo + atomicAdd(&sm[r.x & 511], 1);
        edge8[pos] = make_int2(r.x >> 9, r.y);      // (col, val-bits)
    }
}

// ---------------- SpMM: quarter-wave per row, fp16 gather, 8-deep MLP ----------------
__global__ __launch_bounds__(256) void lg_spmmH(const int* __restrict__ row_start,
                                                const int2* __restrict__ edges,
                                                const h4* __restrict__ xin,
                                                h4* __restrict__ xout) {
    int row  = blockIdx.x * 16 + (threadIdx.x >> 4);
    int lane = threadIdx.x & 15;
    if (row >= NN) return;
    int s = row_start[row];
    int e = row_start[row + 1];
    float4 sum = make_float4(0.f, 0.f, 0.f, 0.f);
    int i = s;
    for (; i + 7 < e; i += 8) {
        int2 E[8];
        h4   X[8];
        #pragma unroll
        for (int k = 0; k < 8; ++k) E[k] = edges[i + k];
        #pragma unroll
        for (int k = 0; k < 8; ++k) X[k] = xin[E[k].x * D4 + lane];
        #pragma unroll
        for (int k = 0; k < 8; ++k) {
            float v = __int_as_float(E[k].y);
            float2 l2 = __half22float2(X[k].a), h2 = __half22float2(X[k].b);
            sum.x += v * l2.x; sum.y += v * l2.y; sum.z += v * h2.x; sum.w += v * h2.y;
        }
    }
    for (; i + 3 < e; i += 4) {
        int2 E[4];
        h4   X[4];
        #pragma unroll
        for (int k = 0; k < 4; ++k) E[k] = edges[i + k];
        #pragma unroll
        for (int k = 0; k < 4; ++k) X[k] = xin[E[k].x * D4 + lane];
        #pragma unroll
        for (int k = 0; k < 4; ++k) {
            float v = __int_as_float(E[k].y);
            float2 l2 = __half22float2(X[k].a), h2 = __half22float2(X[k].b);
            sum.x += v * l2.x; sum.y += v * l2.y; sum.z += v * h2.x; sum.w += v * h2.y;
        }
    }
    for (; i < e; ++i) {
        int2 E0 = edges[i];
        h4 A = xin[E0.x * D4 + lane];
        float v = __int_as_float(E0.y);
        float2 l2 = __half22float2(A.a), h2 = __half22float2(A.b);
        sum.x += v * l2.x; sum.y += v * l2.y; sum.z += v * h2.x; sum.w += v * h2.y;
    }
    h4 o;
    o.a = __floats2half2_rn(sum.x, sum.y);
    o.b = __floats2half2_rn(sum.z, sum.w);
    xout[row * D4 + lane] = o;
}

// final layer: x3 = A*x2 (fp16 gather); out = (x0_fp32 + x1 + x2 + x3) / 4
__global__ __launch_bounds__(256) void lg_finalH(const int* __restrict__ row_start,
                                                 const int2* __restrict__ edges,
                                                 const h4* __restrict__ x2h,
                                                 const h4* __restrict__ x1h,
                                                 const float* __restrict__ ue,
                                                 const float* __restrict__ ie,
                                                 float* __restrict__ out) {
    int row  = blockIdx.x * 16 + (threadIdx.x >> 4);
    int lane = threadIdx.x & 15;
    if (row >= NN) return;
    int s = row_start[row];
    int e = row_start[row + 1];
    float4 sum = make_float4(0.f, 0.f, 0.f, 0.f);
    int i = s;
    for (; i + 7 < e; i += 8) {
        int2 E[8];
        h4   X[8];
        #pragma unroll
        for (int k = 0; k < 8; ++k) E[k] = edges[i + k];
        #pragma unroll
        for (int k = 0; k < 8; ++k) X[k] = x2h[E[k].x * D4 + lane];
        #pragma unroll
        for (int k = 0; k < 8; ++k) {
            float v = __int_as_float(E[k].y);
            float2 l2 = __half22float2(X[k].a), h2 = __half22float2(X[k].b);
            sum.x += v * l2.x; sum.y += v * l2.y; sum.z += v * h2.x; sum.w += v * h2.y;
        }
    }
    for (; i + 3 < e; i += 4) {
        int2 E[4];
        h4   X[4];
        #pragma unroll
        for (int k = 0; k < 4; ++k) E[k] = edges[i + k];
        #pragma unroll
        for (int k = 0; k < 4; ++k) X[k] = x2h[E[k].x * D4 + lane];
        #pragma unroll
        for (int k = 0; k < 4; ++k) {
            float v = __int_as_float(E[k].y);
            float2 l2 = __half22float2(X[k].a), h2 = __half22float2(X[k].b);
            sum.x += v * l2.x; sum.y += v * l2.y; sum.z += v * h2.x; sum.w += v * h2.y;
        }
    }
    for (; i < e; ++i) {
        int2 E0 = edges[i];
        h4 A = x2h[E0.x * D4 + lane];
        float v = __int_as_float(E0.y);
        float2 l2 = __half22float2(A.a), h2 = __half22float2(A.b);
        sum.x += v * l2.x; sum.y += v * l2.y; sum.z += v * h2.x; sum.w += v * h2.y;
    }
    int idx = row * D4 + lane;
    float4 a0 = (row < NUM_USERS) ? ((const float4*)ue)[idx]
                                  : ((const float4*)ie)[idx - NUM_USERS * D4];
    h4 h1 = x1h[idx], h2v = x2h[idx];
    float2 p0 = __half22float2(h1.a), p1 = __half22float2(h1.b);
    float2 q0 = __half22float2(h2v.a), q1 = __half22float2(h2v.b);
    float4 o;
    o.x = (a0.x + p0.x + q0.x + sum.x) * 0.25f;
    o.y = (a0.y + p0.y + q0.y + sum.y) * 0.25f;
    o.z = (a0.z + p1.x + q1.x + sum.z) * 0.25f;
    o.w = (a0.w + p1.y + q1.y + sum.w) * 0.25f;
    ((float4*)out)[idx] = o;
}

// ---------------- launch ----------------
extern "C" void kernel_launch(void* const* d_in, const int* in_sizes, int n_in,
                              void* d_out, int out_size, void* d_ws, size_t ws_size,
                              hipStream_t stream) {
    const float* user_emb = (const float*)d_in[0];
    const float* item_emb = (const float*)d_in[1];
    const float* adj_vals = (const float*)d_in[2];
    const int*   adj_rows = (const int*)d_in[3];
    const int*   adj_cols = (const int*)d_in[4];
    float* out = (float*)d_out;

    char* ws = (char*)d_ws;
    size_t off = 0;
    auto carve = [&](size_t bytes) {
        size_t o = off;
        off += (bytes + 255) & ~size_t(255);
        return (void*)(ws + o);
    };
    h4*   x0h       = (h4*)carve(sizeof(h4) * NN * D4);        // 32 MB
    int2* rec       = (int2*)carve(sizeof(int2) * NNZ_TOT);    // 32 MB (aliases x1h)
    h4*   x1h       = (h4*)rec;                                // rec dead before x1 written
    h4*   x2h       = (h4*)carve(sizeof(h4) * NN * D4);        // 32 MB
    int2* edge8     = (int2*)carve(sizeof(int2) * NNZ_TOT);    // 32 MB
    int*  histG     = (int*)carve(sizeof(int) * HISTN);        // 936 KB
    int*  baseG     = (int*)carve(sizeof(int) * HISTN);        // 936 KB
    int*  row_start = (int*)carve(sizeof(int) * (NN + 1));     // 1 MB
    int*  bsums     = (int*)carve(sizeof(int) * 1024);
    (void)ws_size; (void)in_sizes; (void)n_in; (void)out_size;

    const int nVecBlocks  = (NN * D4 + 255) / 256;             // 15625
    const int nRowBlocks  = (NN + 15) / 16;                    // 15625
    const int nScanBlocks = (HISTN + 255) / 256;               // 934

    lg_cvt<<<nVecBlocks, 256, 0, stream>>>(user_emb, item_emb, x0h);
    lg_histA<<<NBLK, 256, 0, stream>>>(adj_rows, histG);
    lg_scan1<<<nScanBlocks, 256, 0, stream>>>(histG, baseG, bsums, HISTN);
    lg_scan2<<<1, 1024, 0, stream>>>(bsums, nScanBlocks);
    lg_scan3<<<nScanBlocks, 256, 0, stream>>>(baseG, bsums, HISTN);
    lg_scatB<<<NBLK, 256, 0, stream>>>(adj_rows, adj_cols, adj_vals, baseG, rec);
    lg_csrC<<<NBUCK, 1024, 0, stream>>>(rec, baseG, row_start, edge8);

    lg_spmmH<<<nRowBlocks, 256, 0, stream>>>(row_start, edge8, x0h, x1h);   // x1
    lg_spmmH<<<nRowBlocks, 256, 0, stream>>>(row_start, edge8, x1h, x2h);   // x2
    lg_finalH<<<nRowBlocks, 256, 0, stream>>>(row_start, edge8, x2h, x1h,
                                              user_emb, item_emb, out);     // out
}